// Round 6
// baseline (1202.641 us; speedup 1.0000x reference)
//
#include <hip/hip_runtime.h>
#include <math.h>

// Problem constants (NaViT encoder)
#define LNUM 2
#define BB   4
#define NN   2048
#define DIM  768
#define NH   12
#define DH   64
#define MLPD 3072
#define QKVD 2304   // fused q|k|v row stride

typedef __attribute__((ext_vector_type(8))) short bf16x8;
typedef __attribute__((ext_vector_type(4))) float f32x4;
typedef unsigned short ushort_t;

__device__ __forceinline__ ushort_t f2bf(float f) {
    union { float f; unsigned u; } v; v.f = f;
    unsigned r = v.u + 0x7fff + ((v.u >> 16) & 1);  // RNE
    return (ushort_t)(r >> 16);
}
__device__ __forceinline__ float bf2f(ushort_t s) {
    union { unsigned u; float f; } v; v.u = ((unsigned)s) << 16;
    return v.f;
}
__device__ __forceinline__ void gld16(const void* g, void* l) {
    __builtin_amdgcn_global_load_lds(
        (const __attribute__((address_space(1))) void*)g,
        (__attribute__((address_space(3))) void*)l, 16, 0, 0);
}
// tanh-form GELU (max |err| vs exact erf-GELU ~3e-4 — invisible at bf16)
__device__ __forceinline__ float gelu_f(float x) {
    const float y = 0.7978845608028654f * (x + 0.044715f * x * x * x);
    const float t = 1.f - 2.f / (1.f + __expf(2.f * y));  // tanh(y), inf-safe
    return 0.5f * x * (1.f + t);
}

// ---------------------------------------------------------------------------
// Weight convert + transpose: W fp32 [K,N] -> Wt bf16 [N,K]. 32x32 LDS tiles.
// ---------------------------------------------------------------------------
__global__ __launch_bounds__(256) void wconvert_kernel(
    const float* __restrict__ W, ushort_t* __restrict__ Wt, int K, int N)
{
    __shared__ ushort_t t[32][33];
    const int tx = threadIdx.x & 31, ty = threadIdx.x >> 5;  // ty 0..7
    const int nt = blockIdx.x * 32, kt = blockIdx.y * 32;
#pragma unroll
    for (int r = 0; r < 4; r++) {
        const int k = kt + ty + r * 8;
        t[ty + r * 8][tx] = f2bf(W[(size_t)k * N + nt + tx]);
    }
    __syncthreads();
#pragma unroll
    for (int r = 0; r < 4; r++) {
        const int n = nt + ty + r * 8;
        Wt[(size_t)n * K + kt + tx] = t[tx][ty + r * 8];
    }
}

// ---------------------------------------------------------------------------
// LayerNorm over last dim (768). One block (256 thr) per row. OT: float|ushort
// ---------------------------------------------------------------------------
template <typename OT>
__global__ __launch_bounds__(256) void ln_kernel(const float* in, const float* g, OT* out)
{
    const int row = blockIdx.x;
    const int tid = threadIdx.x;
    const float* rp = in + (size_t)row * DIM;
    float vals[3];
    float s = 0.f, s2 = 0.f;
#pragma unroll
    for (int k = 0; k < 3; k++) {
        float v = rp[tid + k * 256];
        vals[k] = v;
        s += v; s2 += v * v;
    }
#pragma unroll
    for (int o = 32; o; o >>= 1) {
        s  += __shfl_xor(s, o);
        s2 += __shfl_xor(s2, o);
    }
    __shared__ float red[8];
    const int wid = tid >> 6;
    if ((tid & 63) == 0) { red[wid] = s; red[wid + 4] = s2; }
    __syncthreads();
    s  = red[0] + red[1] + red[2] + red[3];
    s2 = red[4] + red[5] + red[6] + red[7];
    const float mean = s * (1.f / DIM);
    const float var  = s2 * (1.f / DIM) - mean * mean;
    const float inv  = rsqrtf(var + 1e-5f);
    OT* op = out + (size_t)row * DIM;
#pragma unroll
    for (int k = 0; k < 3; k++) {
        const float v = (vals[k] - mean) * inv * g[tid + k * 256];
        if constexpr (sizeof(OT) == 2) op[tid + k * 256] = f2bf(v);
        else                           op[tid + k * 256] = v;
    }
}

// ---------------------------------------------------------------------------
// BF16 MFMA GEMM: C[M,N] = act(A[M,K] @ Bt[N,K]^T + bias) + resid
// TM x 128 tile (TM = 128 or 64), BK=32, 256 thr = 4 waves (2x2), 16x16x32.
// FRAGMENT-MAJOR LDS staging: the per-lane GLOBAL source is permuted so that
// LDS slot s = block*64 + lane holds (row = block*16 + (lane&15),
// kchunk = lane>>4). Fragment reads are then 1KB contiguous per wave ->
// conflict-free ds_read_b128 and trivial addressing.
// ---------------------------------------------------------------------------
template <int TM>
__global__ __launch_bounds__(256) void gemm_bf(
    const ushort_t* __restrict__ A, const ushort_t* __restrict__ Bt,
    const float* __restrict__ bias, const float* __restrict__ resid,
    void* __restrict__ Cv, int M, int N, int K, int outbf, int act)
{
    constexpr int MF = TM / 32;  // m-frags per wave: 4 (TM=128) or 2 (TM=64)
    __shared__ ushort_t As[TM * 32];
    __shared__ ushort_t Bs[128 * 32];
    const int tid  = threadIdx.x;
    const int w    = tid >> 6, lane = tid & 63;
    const int lq   = lane & 15, quad = lane >> 4;
    const int wm   = w & 1, wn = w >> 1;
    const int tileM = blockIdx.y * TM, tileN = blockIdx.x * 128;

    // staging source coords (fragment-major)
    const int srow = lane & 15, schunk = lane >> 4;
    const ushort_t* ag0 = A  + (size_t)(tileM + w * 16 + srow) * K + schunk * 8;
    const ushort_t* ag1 = A  + (size_t)(tileM + (TM == 128 ? 64 : 0) + w * 16 + srow) * K + schunk * 8;
    const ushort_t* bg0 = Bt + (size_t)(tileN + w * 16 + srow) * K + schunk * 8;
    const ushort_t* bg1 = Bt + (size_t)(tileN + 64 + w * 16 + srow) * K + schunk * 8;
    ushort_t* al0 = As + (w * 64) * 8;
    ushort_t* al1 = As + ((w + 4) * 64) * 8;   // TM=128 only
    ushort_t* bl0 = Bs + (w * 64) * 8;
    ushort_t* bl1 = Bs + ((w + 4) * 64) * 8;

    f32x4 acc[MF][4];
#pragma unroll
    for (int m = 0; m < MF; m++)
#pragma unroll
        for (int n = 0; n < 4; n++) acc[m][n] = (f32x4){0.f, 0.f, 0.f, 0.f};

    for (int kt = 0; kt < K; kt += 32) {
        gld16(ag0 + kt, al0);
        if constexpr (TM == 128) gld16(ag1 + kt, al1);
        gld16(bg0 + kt, bl0);
        gld16(bg1 + kt, bl1);
        __syncthreads();

        bf16x8 af[MF], bf_[4];
#pragma unroll
        for (int m = 0; m < MF; m++)
            af[m] = *(const bf16x8*)&As[((wm * MF + m) * 64 + lane) * 8];
#pragma unroll
        for (int n = 0; n < 4; n++)
            bf_[n] = *(const bf16x8*)&Bs[((wn * 4 + n) * 64 + lane) * 8];
#pragma unroll
        for (int n = 0; n < 4; n++)
#pragma unroll
            for (int m = 0; m < MF; m++)
                acc[m][n] = __builtin_amdgcn_mfma_f32_16x16x32_bf16(af[m], bf_[n], acc[m][n], 0, 0, 0);
        __syncthreads();
    }

    float* Cf = (float*)Cv;
    ushort_t* Cb = (ushort_t*)Cv;
#pragma unroll
    for (int m = 0; m < MF; m++) {
#pragma unroll
        for (int n = 0; n < 4; n++) {
            const int col = tileN + wn * 64 + n * 16 + lq;
            const float bv = bias ? bias[col] : 0.f;
#pragma unroll
            for (int r = 0; r < 4; r++) {
                const int row = tileM + wm * (TM / 2) + m * 16 + quad * 4 + r;
                float v = acc[m][n][r] + bv;
                if (act) v = gelu_f(v);
                const size_t off = (size_t)row * N + col;
                if (resid) v += resid[off];
                if (outbf) Cb[off] = f2bf(v);
                else       Cf[off] = v;
            }
        }
    }
}

// ---------------------------------------------------------------------------
// QK RMSNorm + 2D RoPE, in-place on bf16 at row stride QKVD. One wave per
// (b,n,h) row; lane = dh index. blockIdx.y: 0 -> q (col 0), 1 -> k (col 768).
// ---------------------------------------------------------------------------
__global__ __launch_bounds__(256) void rmsrope_kernel(
    ushort_t* QKV, const float* __restrict__ qg, const float* __restrict__ kg,
    const int* __restrict__ h_idx, const int* __restrict__ w_idx)
{
    const int which = blockIdx.y;
    const float* g = which ? kg : qg;
    ushort_t* X = QKV + which * DIM;

    const int tid  = threadIdx.x;
    const int lane = tid & 63;
    const int r    = blockIdx.x * 4 + (tid >> 6);  // (b*N+n)*H + h
    const int h    = r % NH;
    const int bn   = r / NH;
    const size_t off = (size_t)bn * QKVD + h * DH + lane;

    float v  = bf2f(X[off]);
    float gv = g[h * DH + lane];

    float ss = v * v;
#pragma unroll
    for (int o = 32; o; o >>= 1) ss += __shfl_xor(ss, o);
    float nrm = fmaxf(sqrtf(ss), 1e-12f);
    float val = v / nrm * 8.0f * gv;  // sqrt(DH)=8

    const int idx = (lane < 32) ? h_idx[bn] : w_idx[bn];
    const int f   = lane & 15;
    const float th = (float)idx * powf(10000.f, -(float)f * (1.f / 16.f));
    const float sn = sinf(th), cs = cosf(th);
    const float partner = __shfl_xor(val, 16);
    const float outv = ((lane & 31) < 16) ? (val * cs - partner * sn)
                                          : (val * cs + partner * sn);
    X[off] = f2bf(outv);
}

// ---------------------------------------------------------------------------
// V transpose: qkv v-block [B,N,H,DH] -> Vt [B,H,DH,N] bf16. 32x32 LDS tiles.
// ---------------------------------------------------------------------------
__global__ __launch_bounds__(256) void vtrans_kernel(
    const ushort_t* __restrict__ QKV, ushort_t* __restrict__ Vt)
{
    __shared__ ushort_t t[32][33];
    const int bh = blockIdx.x;
    const int b = bh / NH, h = bh % NH;
    const int d0 = blockIdx.y * 32, n0 = blockIdx.z * 32;
    const int tx = threadIdx.x & 31, ty = threadIdx.x >> 5;
#pragma unroll
    for (int r = 0; r < 4; r++) {
        const int n = n0 + ty + r * 8;
        t[ty + r * 8][tx] = QKV[(size_t)(b * NN + n) * QKVD + 2 * DIM + h * DH + d0 + tx];
    }
    __syncthreads();
#pragma unroll
    for (int r = 0; r < 4; r++) {
        const int d = d0 + ty + r * 8;
        Vt[((size_t)(b * NH + h) * DH + d) * NN + n0 + tx] = t[tx][ty + r * 8];
    }
}

// ---------------------------------------------------------------------------
// BF16 MFMA flash attention, streaming softmax (fixed max = 0; QK-RMSNorm
// bounds |s| <= 64). Block = 4 waves, 64 queries (16/wave). grid (B*H, N/64).
// ---------------------------------------------------------------------------
__global__ __launch_bounds__(256) void attn_kernel(
    const ushort_t* __restrict__ QKV, const ushort_t* __restrict__ Vt_g,
    const int* __restrict__ lengths, ushort_t* __restrict__ O)
{
    __shared__ ushort_t Ks[64 * 64];
    __shared__ ushort_t Vs[64 * 64];
    __shared__ ushort_t Ps[4][16][76];

    const int bh = blockIdx.x;
    const int b  = bh / NH;
    const int h  = bh % NH;
    const int qbase = blockIdx.y * 64;
    const int tid  = threadIdx.x;
    const int w    = tid >> 6;
    const int lane = tid & 63;
    const int lq   = lane & 15;
    const int quad = lane >> 4;
    const int len  = lengths[b];

    const int qrow = qbase + w * 16 + lq;
    const ushort_t* qp = QKV + (size_t)(b * NN + qrow) * QKVD + h * DH + quad * 8;
    bf16x8 aq0 = *(const bf16x8*)(qp);
    bf16x8 aq1 = *(const bf16x8*)(qp + 32);

    const int e0 = tid, e1 = tid + 256;
    const int r0 = e0 >> 3, c80 = e0 & 7;
    const int r1 = e1 >> 3, c81 = e1 & 7;
    const int g0 = (c80 ^ (r0 & 7) ^ (r0 >> 3)) & 7;
    const int g1 = (c81 ^ (r1 & 7) ^ (r1 >> 3)) & 7;
    const ushort_t* kg0 = QKV + (size_t)(b * NN + r0) * QKVD + DIM + h * DH + g0 * 8;
    const ushort_t* kg1 = QKV + (size_t)(b * NN + r1) * QKVD + DIM + h * DH + g1 * 8;
    const ushort_t* vg0 = Vt_g + ((size_t)(b * NH + h) * DH + r0) * NN + g0 * 8;
    const ushort_t* vg1 = Vt_g + ((size_t)(b * NH + h) * DH + r1) * NN + g1 * 8;
    ushort_t* kl0 = Ks + (w * 64) * 8;
    ushort_t* kl1 = Ks + (256 + w * 64) * 8;
    ushort_t* vl0 = Vs + (w * 64) * 8;
    ushort_t* vl1 = Vs + (256 + w * 64) * 8;

    f32x4 oacc[4];
#pragma unroll
    for (int t4 = 0; t4 < 4; t4++) oacc[t4] = (f32x4){0.f, 0.f, 0.f, 0.f};
    float lsum = 0.f;

    const int ntiles = (len + 63) >> 6;
    for (int t = 0; t < ntiles; t++) {
        const int j0 = t * 64;
        gld16(kg0 + (size_t)j0 * QKVD, kl0);
        gld16(kg1 + (size_t)j0 * QKVD, kl1);
        gld16(vg0 + j0, vl0);
        gld16(vg1 + j0, vl1);
        __syncthreads();

        f32x4 s[4];
#pragma unroll
        for (int n = 0; n < 4; n++) {
            const int krow = n * 16 + lq;
            const int hashk = (krow & 7) ^ (krow >> 3);
            bf16x8 ak0 = *(const bf16x8*)&Ks[(krow * 8 + ((quad ^ hashk) & 7)) * 8];
            bf16x8 ak1 = *(const bf16x8*)&Ks[(krow * 8 + (((quad + 4) ^ hashk) & 7)) * 8];
            f32x4 acc = (f32x4){0.f, 0.f, 0.f, 0.f};
            acc = __builtin_amdgcn_mfma_f32_16x16x32_bf16(ak0, aq0, acc, 0, 0, 0);
            acc = __builtin_amdgcn_mfma_f32_16x16x32_bf16(ak1, aq1, acc, 0, 0, 0);
            s[n] = acc;
        }

        float p[4][4];
#pragma unroll
        for (int n = 0; n < 4; n++) {
            const int keyb = j0 + n * 16 + quad * 4;
#pragma unroll
            for (int r = 0; r < 4; r++) {
                float pv = __expf(s[n][r]);
                pv = (keyb + r < len) ? pv : 0.f;
                p[n][r] = pv;
                lsum += pv;
            }
        }

#pragma unroll
        for (int n = 0; n < 4; n++) {
            const unsigned lo = (unsigned)f2bf(p[n][0]) | ((unsigned)f2bf(p[n][1]) << 16);
            const unsigned hi = (unsigned)f2bf(p[n][2]) | ((unsigned)f2bf(p[n][3]) << 16);
            *(uint2*)&Ps[w][lq][n * 16 + quad * 4] = make_uint2(lo, hi);
        }
        asm volatile("s_waitcnt lgkmcnt(0)" ::: "memory");
        bf16x8 ap0 = *(const bf16x8*)&Ps[w][lq][quad * 8];
        bf16x8 ap1 = *(const bf16x8*)&Ps[w][lq][32 + quad * 8];

#pragma unroll
        for (int t4 = 0; t4 < 4; t4++) {
            const int vrow = t4 * 16 + lq;
            const int hashv = (vrow & 7) ^ (vrow >> 3);
            bf16x8 bv0 = *(const bf16x8*)&Vs[(vrow * 8 + ((quad ^ hashv) & 7)) * 8];
            bf16x8 bv1 = *(const bf16x8*)&Vs[(vrow * 8 + (((quad + 4) ^ hashv) & 7)) * 8];
            oacc[t4] = __builtin_amdgcn_mfma_f32_16x16x32_bf16(ap0, bv0, oacc[t4], 0, 0, 0);
            oacc[t4] = __builtin_amdgcn_mfma_f32_16x16x32_bf16(ap1, bv1, oacc[t4], 0, 0, 0);
        }
        __syncthreads();
    }

    lsum += __shfl_xor(lsum, 16);
    lsum += __shfl_xor(lsum, 32);
    float invq[4];
#pragma unroll
    for (int r = 0; r < 4; r++) invq[r] = 1.f / __shfl(lsum, quad * 4 + r);

#pragma unroll
    for (int t4 = 0; t4 < 4; t4++) {
#pragma unroll
        for (int r = 0; r < 4; r++) {
            const int qr = qbase + w * 16 + quad * 4 + r;
            O[((size_t)(b * NN + qr)) * DIM + h * DH + t4 * 16 + lq] = f2bf(oacc[t4][r] * invq[r]);
        }
    }
}

// ---------------------------------------------------------------------------
__global__ __launch_bounds__(256) void mask_kernel(const int* __restrict__ lengths, float* __restrict__ out)
{
    const int i = blockIdx.x * 256 + threadIdx.x;
    const int b = i >> 11;
    const int n = i & (NN - 1);
    out[i] = (n < lengths[b]) ? 1.f : 0.f;
}

// ---------------------------------------------------------------------------
extern "C" void kernel_launch(void* const* d_in, const int* in_sizes, int n_in,
                              void* d_out, int out_size, void* d_ws, size_t ws_size,
                              hipStream_t stream)
{
    const float* patches    = (const float*)d_in[0];
    const float* pe_ln1_g   = (const float*)d_in[1];
    const float* pe_W       = (const float*)d_in[2];
    const float* pe_b       = (const float*)d_in[3];
    const float* pe_ln2_g   = (const float*)d_in[4];
    const float* attn_ln_g  = (const float*)d_in[5];
    const float* qn_g       = (const float*)d_in[6];
    const float* kn_g       = (const float*)d_in[7];
    const float* Wq         = (const float*)d_in[8];
    const float* Wkv        = (const float*)d_in[9];
    const float* Wo         = (const float*)d_in[10];
    const float* ff_ln_g    = (const float*)d_in[11];
    const float* W1         = (const float*)d_in[12];
    const float* b1         = (const float*)d_in[13];
    const float* W2         = (const float*)d_in[14];
    const float* b2         = (const float*)d_in[15];
    const float* final_ln_g = (const float*)d_in[16];
    const int*   h_idx      = (const int*)d_in[17];
    const int*   w_idx      = (const int*)d_in[18];
    const int*   lengths    = (const int*)d_in[19];

    float* out = (float*)d_out;
    char*  p   = (char*)d_ws;

    const size_t MB = 1024 * 1024;
    ushort_t* wbf = (ushort_t*)p;                       // 29.5 MB
    ushort_t* peWt = wbf;
    size_t woff = (size_t)DIM * DIM;
    ushort_t* Wqkvt[LNUM], *Wot[LNUM], *W1t[LNUM], *W2t[LNUM];
    for (int i = 0; i < LNUM; i++) {
        Wqkvt[i] = wbf + woff; woff += (size_t)QKVD * DIM;  // q rows then kv rows
        Wot[i]   = wbf + woff; woff += (size_t)DIM * DIM;
        W1t[i]   = wbf + woff; woff += (size_t)DIM * MLPD;
        W2t[i]   = wbf + woff; woff += (size_t)MLPD * DIM;
    }
    ushort_t* xnbf = (ushort_t*)(p + 30 * MB);          // [8192,768]  12.6 MB
    ushort_t* qkv  = (ushort_t*)(p + 43 * MB);          // [8192,2304] 37.7 MB
    ushort_t* aob  = (ushort_t*)(p + 82 * MB);          // [8192,768]  12.6 MB
    ushort_t* hb   = (ushort_t*)(p + 43 * MB);          // [8192,3072] 50.3 MB (qkv dead)
    float*    peF  = (float*)(p + 43 * MB);             // [8192,768] fp32 (pe only)
    ushort_t* vtg  = (ushort_t*)(p + 96 * MB);          // [B,H,DH,N]  12.6 MB

    const int ROWS = BB * NN;  // 8192
    dim3 blk(256);

    // ---- weight convert + transpose (bf16) ----
    wconvert_kernel<<<dim3(DIM / 32, DIM / 32), blk, 0, stream>>>(pe_W, peWt, DIM, DIM);
    for (int i = 0; i < LNUM; i++) {
        wconvert_kernel<<<dim3(DIM / 32, DIM / 32), blk, 0, stream>>>(
            Wq + (size_t)i * DIM * DIM, Wqkvt[i], DIM, DIM);
        wconvert_kernel<<<dim3(2 * DIM / 32, DIM / 32), blk, 0, stream>>>(
            Wkv + (size_t)i * DIM * 2 * DIM, Wqkvt[i] + (size_t)DIM * DIM, DIM, 2 * DIM);
        wconvert_kernel<<<dim3(DIM / 32, DIM / 32), blk, 0, stream>>>(
            Wo + (size_t)i * DIM * DIM, Wot[i], DIM, DIM);
        wconvert_kernel<<<dim3(MLPD / 32, DIM / 32), blk, 0, stream>>>(
            W1 + (size_t)i * DIM * MLPD, W1t[i], DIM, MLPD);
        wconvert_kernel<<<dim3(DIM / 32, MLPD / 32), blk, 0, stream>>>(
            W2 + (size_t)i * MLPD * DIM, W2t[i], MLPD, DIM);
    }

    // ---- patch embedding: LN -> GEMM(+bias) -> LN ----
    ln_kernel<ushort_t><<<ROWS, blk, 0, stream>>>(patches, pe_ln1_g, xnbf);
    gemm_bf<64><<<dim3(DIM / 128, ROWS / 64), blk, 0, stream>>>(
        xnbf, peWt, pe_b, nullptr, peF, ROWS, DIM, DIM, 0, 0);
    ln_kernel<float><<<ROWS, blk, 0, stream>>>(peF, pe_ln2_g, out);

    float* x = out;  // residual stream lives in d_out
    for (int i = 0; i < LNUM; i++) {
        ln_kernel<ushort_t><<<ROWS, blk, 0, stream>>>(x, attn_ln_g + i * DIM, xnbf);
        gemm_bf<128><<<dim3(QKVD / 128, ROWS / 128), blk, 0, stream>>>(
            xnbf, Wqkvt[i], nullptr, nullptr, qkv, ROWS, QKVD, DIM, 1, 0);
        rmsrope_kernel<<<dim3(ROWS * NH / 4, 2), blk, 0, stream>>>(
            qkv, qn_g + i * NH * DH, kn_g + i * NH * DH, h_idx, w_idx);
        vtrans_kernel<<<dim3(BB * NH, DH / 32, NN / 32), blk, 0, stream>>>(qkv, vtg);
        attn_kernel<<<dim3(BB * NH, NN / 64), blk, 0, stream>>>(
            qkv, vtg, lengths, aob);
        gemm_bf<64><<<dim3(DIM / 128, ROWS / 64), blk, 0, stream>>>(
            aob, Wot[i], nullptr, x, x, ROWS, DIM, DIM, 0, 0);
        ln_kernel<ushort_t><<<ROWS, blk, 0, stream>>>(x, ff_ln_g + i * DIM, xnbf);
        gemm_bf<128><<<dim3(MLPD / 128, ROWS / 128), blk, 0, stream>>>(
            xnbf, W1t[i], b1 + i * MLPD, nullptr, hb, ROWS, MLPD, DIM, 1, 1);
        gemm_bf<64><<<dim3(DIM / 128, ROWS / 64), blk, 0, stream>>>(
            hb, W2t[i], b2 + i * DIM, x, x, ROWS, DIM, MLPD, 0, 0);
    }
    ln_kernel<float><<<ROWS, blk, 0, stream>>>(x, final_ln_g, out);
    mask_kernel<<<ROWS / 256, blk, 0, stream>>>(lengths, out + (size_t)ROWS * DIM);
}

// Round 7
// 1005.668 us; speedup vs baseline: 1.1959x; 1.1959x over previous
//
#include <hip/hip_runtime.h>
#include <math.h>

// Problem constants (NaViT encoder)
#define LNUM 2
#define BB   4
#define NN   2048
#define DIM  768
#define NH   12
#define DH   64
#define MLPD 3072
#define QKVD 2304   // fused q|k|v row stride

typedef __attribute__((ext_vector_type(8))) short bf16x8;
typedef __attribute__((ext_vector_type(4))) float f32x4;
typedef unsigned short ushort_t;

__device__ __forceinline__ ushort_t f2bf(float f) {
    union { float f; unsigned u; } v; v.f = f;
    unsigned r = v.u + 0x7fff + ((v.u >> 16) & 1);  // RNE
    return (ushort_t)(r >> 16);
}
__device__ __forceinline__ float bf2f(ushort_t s) {
    union { unsigned u; float f; } v; v.u = ((unsigned)s) << 16;
    return v.f;
}
__device__ __forceinline__ void gld16(const void* g, void* l) {
    __builtin_amdgcn_global_load_lds(
        (const __attribute__((address_space(1))) void*)g,
        (__attribute__((address_space(3))) void*)l, 16, 0, 0);
}
// tanh-form GELU (max |err| vs exact erf-GELU ~3e-4 — invisible at bf16)
__device__ __forceinline__ float gelu_f(float x) {
    const float y = 0.7978845608028654f * (x + 0.044715f * x * x * x);
    const float t = 1.f - 2.f / (1.f + __expf(2.f * y));  // tanh(y), inf-safe
    return 0.5f * x * (1.f + t);
}

// ---------------------------------------------------------------------------
// Weight convert + transpose: W fp32 [K,N] -> Wt bf16 [N,K]. 32x32 LDS tiles.
// ---------------------------------------------------------------------------
__global__ __launch_bounds__(256) void wconvert_kernel(
    const float* __restrict__ W, ushort_t* __restrict__ Wt, int K, int N)
{
    __shared__ ushort_t t[32][33];
    const int tx = threadIdx.x & 31, ty = threadIdx.x >> 5;  // ty 0..7
    const int nt = blockIdx.x * 32, kt = blockIdx.y * 32;
#pragma unroll
    for (int r = 0; r < 4; r++) {
        const int k = kt + ty + r * 8;
        t[ty + r * 8][tx] = f2bf(W[(size_t)k * N + nt + tx]);
    }
    __syncthreads();
#pragma unroll
    for (int r = 0; r < 4; r++) {
        const int n = nt + ty + r * 8;
        Wt[(size_t)n * K + kt + tx] = t[tx][ty + r * 8];
    }
}

// ---------------------------------------------------------------------------
// LayerNorm over last dim (768). One block (256 thr) per row. OT: float|ushort
// ---------------------------------------------------------------------------
template <typename OT>
__global__ __launch_bounds__(256) void ln_kernel(const float* in, const float* g, OT* out)
{
    const int row = blockIdx.x;
    const int tid = threadIdx.x;
    const float* rp = in + (size_t)row * DIM;
    float vals[3];
    float s = 0.f, s2 = 0.f;
#pragma unroll
    for (int k = 0; k < 3; k++) {
        float v = rp[tid + k * 256];
        vals[k] = v;
        s += v; s2 += v * v;
    }
#pragma unroll
    for (int o = 32; o; o >>= 1) {
        s  += __shfl_xor(s, o);
        s2 += __shfl_xor(s2, o);
    }
    __shared__ float red[8];
    const int wid = tid >> 6;
    if ((tid & 63) == 0) { red[wid] = s; red[wid + 4] = s2; }
    __syncthreads();
    s  = red[0] + red[1] + red[2] + red[3];
    s2 = red[4] + red[5] + red[6] + red[7];
    const float mean = s * (1.f / DIM);
    const float var  = s2 * (1.f / DIM) - mean * mean;
    const float inv  = rsqrtf(var + 1e-5f);
    OT* op = out + (size_t)row * DIM;
#pragma unroll
    for (int k = 0; k < 3; k++) {
        const float v = (vals[k] - mean) * inv * g[tid + k * 256];
        if constexpr (sizeof(OT) == 2) op[tid + k * 256] = f2bf(v);
        else                           op[tid + k * 256] = v;
    }
}

// ---------------------------------------------------------------------------
// BF16 MFMA GEMM: C[M,N] = act(A[M,K] @ Bt[N,K]^T + bias) + resid
// TM x 128 tile, BK=64, 256 thr = 4 waves (2x2), 16x16x32 MFMA.
// Staging: 8 lanes cover one row's 128B (two 64B lines, fully coalesced);
// each lane's chunk index is XOR-swizzled with row&7, so fragment reads
// (slot = row*8 + (chunk ^ (lq&7))) hit each bank-group exactly 2x (free).
// ---------------------------------------------------------------------------
template <int TM>
__global__ __launch_bounds__(256) void gemm_bf(
    const ushort_t* __restrict__ A, const ushort_t* __restrict__ Bt,
    const float* __restrict__ bias, const float* __restrict__ resid,
    void* __restrict__ Cv, int M, int N, int K, int outbf, int act)
{
    constexpr int MF = TM / 32;  // m-frags per wave: 4 (TM=128) or 2 (TM=64)
    constexpr int AG = TM / 32;  // A staging groups of 32 rows
    __shared__ ushort_t As[TM * 64];
    __shared__ ushort_t Bs[128 * 64];
    const int tid  = threadIdx.x;
    const int w    = tid >> 6, lane = tid & 63;
    const int lq   = lane & 15, quad = lane >> 4;
    const int wm   = w & 1, wn = w >> 1;
    const int tileM = blockIdx.y * TM, tileN = blockIdx.x * 128;

    // staging coords: row-within-group = w*8 + (lane>>3); chunk = (lane&7)^srow
    const int srow   = lane >> 3;                 // 0..7
    const int schunk = (lane & 7) ^ srow;         // swizzled k-chunk (8 ushorts)
    const ushort_t* agp[AG];
    const ushort_t* bgp[4];
#pragma unroll
    for (int g = 0; g < AG; g++)
        agp[g] = A + (size_t)(tileM + g * 32 + w * 8 + srow) * K + schunk * 8;
#pragma unroll
    for (int g = 0; g < 4; g++)
        bgp[g] = Bt + (size_t)(tileN + g * 32 + w * 8 + srow) * K + schunk * 8;

    f32x4 acc[MF][4];
#pragma unroll
    for (int m = 0; m < MF; m++)
#pragma unroll
        for (int n = 0; n < 4; n++) acc[m][n] = (f32x4){0.f, 0.f, 0.f, 0.f};

    const int fsw0 = (quad ^ (lq & 7)) * 8;       // chunk quad   slot offset
    const int fsw1 = ((quad ^ (lq & 7)) ^ 4) * 8; // chunk quad+4 slot offset

    for (int kt = 0; kt < K; kt += 64) {
#pragma unroll
        for (int g = 0; g < AG; g++)
            gld16(agp[g] + kt, As + (g * 32 + w * 8) * 64);
#pragma unroll
        for (int g = 0; g < 4; g++)
            gld16(bgp[g] + kt, Bs + (g * 32 + w * 8) * 64);
        __syncthreads();

        bf16x8 af0[MF], af1[MF], bf0[4], bf1[4];
#pragma unroll
        for (int m = 0; m < MF; m++) {
            const int base = ((wm * MF + m) * 16 + lq) * 64;
            af0[m] = *(const bf16x8*)&As[base + fsw0];
            af1[m] = *(const bf16x8*)&As[base + fsw1];
        }
#pragma unroll
        for (int n = 0; n < 4; n++) {
            const int base = ((wn * 4 + n) * 16 + lq) * 64;
            bf0[n] = *(const bf16x8*)&Bs[base + fsw0];
            bf1[n] = *(const bf16x8*)&Bs[base + fsw1];
        }
#pragma unroll
        for (int n = 0; n < 4; n++)
#pragma unroll
            for (int m = 0; m < MF; m++) {
                acc[m][n] = __builtin_amdgcn_mfma_f32_16x16x32_bf16(af0[m], bf0[n], acc[m][n], 0, 0, 0);
                acc[m][n] = __builtin_amdgcn_mfma_f32_16x16x32_bf16(af1[m], bf1[n], acc[m][n], 0, 0, 0);
            }
        __syncthreads();
    }

    float* Cf = (float*)Cv;
    ushort_t* Cb = (ushort_t*)Cv;
#pragma unroll
    for (int m = 0; m < MF; m++) {
#pragma unroll
        for (int n = 0; n < 4; n++) {
            const int col = tileN + wn * 64 + n * 16 + lq;
            const float bv = bias ? bias[col] : 0.f;
#pragma unroll
            for (int r = 0; r < 4; r++) {
                const int row = tileM + wm * (TM / 2) + m * 16 + quad * 4 + r;
                float v = acc[m][n][r] + bv;
                if (act) v = gelu_f(v);
                const size_t off = (size_t)row * N + col;
                if (resid) v += resid[off];
                if (outbf) Cb[off] = f2bf(v);
                else       Cf[off] = v;
            }
        }
    }
}

// ---------------------------------------------------------------------------
// QK RMSNorm + 2D RoPE, in-place on bf16 at row stride QKVD. One wave per
// (b,n,h) row; lane = dh index. blockIdx.y: 0 -> q (col 0), 1 -> k (col 768).
// ---------------------------------------------------------------------------
__global__ __launch_bounds__(256) void rmsrope_kernel(
    ushort_t* QKV, const float* __restrict__ qg, const float* __restrict__ kg,
    const int* __restrict__ h_idx, const int* __restrict__ w_idx)
{
    const int which = blockIdx.y;
    const float* g = which ? kg : qg;
    ushort_t* X = QKV + which * DIM;

    const int tid  = threadIdx.x;
    const int lane = tid & 63;
    const int r    = blockIdx.x * 4 + (tid >> 6);  // (b*N+n)*H + h
    const int h    = r % NH;
    const int bn   = r / NH;
    const size_t off = (size_t)bn * QKVD + h * DH + lane;

    float v  = bf2f(X[off]);
    float gv = g[h * DH + lane];

    float ss = v * v;
#pragma unroll
    for (int o = 32; o; o >>= 1) ss += __shfl_xor(ss, o);
    float nrm = fmaxf(sqrtf(ss), 1e-12f);
    float val = v / nrm * 8.0f * gv;  // sqrt(DH)=8

    const int idx = (lane < 32) ? h_idx[bn] : w_idx[bn];
    const int f   = lane & 15;
    const float th = (float)idx * powf(10000.f, -(float)f * (1.f / 16.f));
    const float sn = sinf(th), cs = cosf(th);
    const float partner = __shfl_xor(val, 16);
    const float outv = ((lane & 31) < 16) ? (val * cs - partner * sn)
                                          : (val * cs + partner * sn);
    X[off] = f2bf(outv);
}

// ---------------------------------------------------------------------------
// V transpose: qkv v-block [B,N,H,DH] -> Vt [B,H,DH,N] bf16. 32x32 LDS tiles.
// ---------------------------------------------------------------------------
__global__ __launch_bounds__(256) void vtrans_kernel(
    const ushort_t* __restrict__ QKV, ushort_t* __restrict__ Vt)
{
    __shared__ ushort_t t[32][33];
    const int bh = blockIdx.x;
    const int b = bh / NH, h = bh % NH;
    const int d0 = blockIdx.y * 32, n0 = blockIdx.z * 32;
    const int tx = threadIdx.x & 31, ty = threadIdx.x >> 5;
#pragma unroll
    for (int r = 0; r < 4; r++) {
        const int n = n0 + ty + r * 8;
        t[ty + r * 8][tx] = QKV[(size_t)(b * NN + n) * QKVD + 2 * DIM + h * DH + d0 + tx];
    }
    __syncthreads();
#pragma unroll
    for (int r = 0; r < 4; r++) {
        const int d = d0 + ty + r * 8;
        Vt[((size_t)(b * NH + h) * DH + d) * NN + n0 + tx] = t[tx][ty + r * 8];
    }
}

// ---------------------------------------------------------------------------
// BF16 MFMA flash attention, streaming softmax (fixed max = 0; QK-RMSNorm
// bounds |s| <= 64). Block = 4 waves, 64 queries (16/wave). grid (B*H, N/64).
// ---------------------------------------------------------------------------
__global__ __launch_bounds__(256) void attn_kernel(
    const ushort_t* __restrict__ QKV, const ushort_t* __restrict__ Vt_g,
    const int* __restrict__ lengths, ushort_t* __restrict__ O)
{
    __shared__ ushort_t Ks[64 * 64];
    __shared__ ushort_t Vs[64 * 64];
    __shared__ ushort_t Ps[4][16][76];

    const int bh = blockIdx.x;
    const int b  = bh / NH;
    const int h  = bh % NH;
    const int qbase = blockIdx.y * 64;
    const int tid  = threadIdx.x;
    const int w    = tid >> 6;
    const int lane = tid & 63;
    const int lq   = lane & 15;
    const int quad = lane >> 4;
    const int len  = lengths[b];

    const int qrow = qbase + w * 16 + lq;
    const ushort_t* qp = QKV + (size_t)(b * NN + qrow) * QKVD + h * DH + quad * 8;
    bf16x8 aq0 = *(const bf16x8*)(qp);
    bf16x8 aq1 = *(const bf16x8*)(qp + 32);

    const int e0 = tid, e1 = tid + 256;
    const int r0 = e0 >> 3, c80 = e0 & 7;
    const int r1 = e1 >> 3, c81 = e1 & 7;
    const int g0 = (c80 ^ (r0 & 7) ^ (r0 >> 3)) & 7;
    const int g1 = (c81 ^ (r1 & 7) ^ (r1 >> 3)) & 7;
    const ushort_t* kg0 = QKV + (size_t)(b * NN + r0) * QKVD + DIM + h * DH + g0 * 8;
    const ushort_t* kg1 = QKV + (size_t)(b * NN + r1) * QKVD + DIM + h * DH + g1 * 8;
    const ushort_t* vg0 = Vt_g + ((size_t)(b * NH + h) * DH + r0) * NN + g0 * 8;
    const ushort_t* vg1 = Vt_g + ((size_t)(b * NH + h) * DH + r1) * NN + g1 * 8;
    ushort_t* kl0 = Ks + (w * 64) * 8;
    ushort_t* kl1 = Ks + (256 + w * 64) * 8;
    ushort_t* vl0 = Vs + (w * 64) * 8;
    ushort_t* vl1 = Vs + (256 + w * 64) * 8;

    f32x4 oacc[4];
#pragma unroll
    for (int t4 = 0; t4 < 4; t4++) oacc[t4] = (f32x4){0.f, 0.f, 0.f, 0.f};
    float lsum = 0.f;

    const int ntiles = (len + 63) >> 6;
    for (int t = 0; t < ntiles; t++) {
        const int j0 = t * 64;
        gld16(kg0 + (size_t)j0 * QKVD, kl0);
        gld16(kg1 + (size_t)j0 * QKVD, kl1);
        gld16(vg0 + j0, vl0);
        gld16(vg1 + j0, vl1);
        __syncthreads();

        f32x4 s[4];
#pragma unroll
        for (int n = 0; n < 4; n++) {
            const int krow = n * 16 + lq;
            const int hashk = (krow & 7) ^ (krow >> 3);
            bf16x8 ak0 = *(const bf16x8*)&Ks[(krow * 8 + ((quad ^ hashk) & 7)) * 8];
            bf16x8 ak1 = *(const bf16x8*)&Ks[(krow * 8 + (((quad + 4) ^ hashk) & 7)) * 8];
            f32x4 acc = (f32x4){0.f, 0.f, 0.f, 0.f};
            acc = __builtin_amdgcn_mfma_f32_16x16x32_bf16(ak0, aq0, acc, 0, 0, 0);
            acc = __builtin_amdgcn_mfma_f32_16x16x32_bf16(ak1, aq1, acc, 0, 0, 0);
            s[n] = acc;
        }

        float p[4][4];
#pragma unroll
        for (int n = 0; n < 4; n++) {
            const int keyb = j0 + n * 16 + quad * 4;
#pragma unroll
            for (int r = 0; r < 4; r++) {
                float pv = __expf(s[n][r]);
                pv = (keyb + r < len) ? pv : 0.f;
                p[n][r] = pv;
                lsum += pv;
            }
        }

#pragma unroll
        for (int n = 0; n < 4; n++) {
            const unsigned lo = (unsigned)f2bf(p[n][0]) | ((unsigned)f2bf(p[n][1]) << 16);
            const unsigned hi = (unsigned)f2bf(p[n][2]) | ((unsigned)f2bf(p[n][3]) << 16);
            *(uint2*)&Ps[w][lq][n * 16 + quad * 4] = make_uint2(lo, hi);
        }
        asm volatile("s_waitcnt lgkmcnt(0)" ::: "memory");
        bf16x8 ap0 = *(const bf16x8*)&Ps[w][lq][quad * 8];
        bf16x8 ap1 = *(const bf16x8*)&Ps[w][lq][32 + quad * 8];

#pragma unroll
        for (int t4 = 0; t4 < 4; t4++) {
            const int vrow = t4 * 16 + lq;
            const int hashv = (vrow & 7) ^ (vrow >> 3);
            bf16x8 bv0 = *(const bf16x8*)&Vs[(vrow * 8 + ((quad ^ hashv) & 7)) * 8];
            bf16x8 bv1 = *(const bf16x8*)&Vs[(vrow * 8 + (((quad + 4) ^ hashv) & 7)) * 8];
            oacc[t4] = __builtin_amdgcn_mfma_f32_16x16x32_bf16(ap0, bv0, oacc[t4], 0, 0, 0);
            oacc[t4] = __builtin_amdgcn_mfma_f32_16x16x32_bf16(ap1, bv1, oacc[t4], 0, 0, 0);
        }
        __syncthreads();
    }

    lsum += __shfl_xor(lsum, 16);
    lsum += __shfl_xor(lsum, 32);
    float invq[4];
#pragma unroll
    for (int r = 0; r < 4; r++) invq[r] = 1.f / __shfl(lsum, quad * 4 + r);

#pragma unroll
    for (int t4 = 0; t4 < 4; t4++) {
#pragma unroll
        for (int r = 0; r < 4; r++) {
            const int qr = qbase + w * 16 + quad * 4 + r;
            O[((size_t)(b * NN + qr)) * DIM + h * DH + t4 * 16 + lq] = f2bf(oacc[t4][r] * invq[r]);
        }
    }
}

// ---------------------------------------------------------------------------
__global__ __launch_bounds__(256) void mask_kernel(const int* __restrict__ lengths, float* __restrict__ out)
{
    const int i = blockIdx.x * 256 + threadIdx.x;
    const int b = i >> 11;
    const int n = i & (NN - 1);
    out[i] = (n < lengths[b]) ? 1.f : 0.f;
}

// ---------------------------------------------------------------------------
extern "C" void kernel_launch(void* const* d_in, const int* in_sizes, int n_in,
                              void* d_out, int out_size, void* d_ws, size_t ws_size,
                              hipStream_t stream)
{
    const float* patches    = (const float*)d_in[0];
    const float* pe_ln1_g   = (const float*)d_in[1];
    const float* pe_W       = (const float*)d_in[2];
    const float* pe_b       = (const float*)d_in[3];
    const float* pe_ln2_g   = (const float*)d_in[4];
    const float* attn_ln_g  = (const float*)d_in[5];
    const float* qn_g       = (const float*)d_in[6];
    const float* kn_g       = (const float*)d_in[7];
    const float* Wq         = (const float*)d_in[8];
    const float* Wkv        = (const float*)d_in[9];
    const float* Wo         = (const float*)d_in[10];
    const float* ff_ln_g    = (const float*)d_in[11];
    const float* W1         = (const float*)d_in[12];
    const float* b1         = (const float*)d_in[13];
    const float* W2         = (const float*)d_in[14];
    const float* b2         = (const float*)d_in[15];
    const float* final_ln_g = (const float*)d_in[16];
    const int*   h_idx      = (const int*)d_in[17];
    const int*   w_idx      = (const int*)d_in[18];
    const int*   lengths    = (const int*)d_in[19];

    float* out = (float*)d_out;
    char*  p   = (char*)d_ws;

    const size_t MB = 1024 * 1024;
    ushort_t* wbf = (ushort_t*)p;                       // 29.5 MB
    ushort_t* peWt = wbf;
    size_t woff = (size_t)DIM * DIM;
    ushort_t* Wqkvt[LNUM], *Wot[LNUM], *W1t[LNUM], *W2t[LNUM];
    for (int i = 0; i < LNUM; i++) {
        Wqkvt[i] = wbf + woff; woff += (size_t)QKVD * DIM;  // q rows then kv rows
        Wot[i]   = wbf + woff; woff += (size_t)DIM * DIM;
        W1t[i]   = wbf + woff; woff += (size_t)DIM * MLPD;
        W2t[i]   = wbf + woff; woff += (size_t)MLPD * DIM;
    }
    ushort_t* xnbf = (ushort_t*)(p + 30 * MB);          // [8192,768]  12.6 MB
    ushort_t* qkv  = (ushort_t*)(p + 43 * MB);          // [8192,2304] 37.7 MB
    ushort_t* aob  = (ushort_t*)(p + 82 * MB);          // [8192,768]  12.6 MB
    ushort_t* hb   = (ushort_t*)(p + 43 * MB);          // [8192,3072] 50.3 MB (qkv dead)
    float*    peF  = (float*)(p + 43 * MB);             // [8192,768] fp32 (pe only)
    ushort_t* vtg  = (ushort_t*)(p + 96 * MB);          // [B,H,DH,N]  12.6 MB

    const int ROWS = BB * NN;  // 8192
    dim3 blk(256);

    // ---- weight convert + transpose (bf16) ----
    wconvert_kernel<<<dim3(DIM / 32, DIM / 32), blk, 0, stream>>>(pe_W, peWt, DIM, DIM);
    for (int i = 0; i < LNUM; i++) {
        wconvert_kernel<<<dim3(DIM / 32, DIM / 32), blk, 0, stream>>>(
            Wq + (size_t)i * DIM * DIM, Wqkvt[i], DIM, DIM);
        wconvert_kernel<<<dim3(2 * DIM / 32, DIM / 32), blk, 0, stream>>>(
            Wkv + (size_t)i * DIM * 2 * DIM, Wqkvt[i] + (size_t)DIM * DIM, DIM, 2 * DIM);
        wconvert_kernel<<<dim3(DIM / 32, DIM / 32), blk, 0, stream>>>(
            Wo + (size_t)i * DIM * DIM, Wot[i], DIM, DIM);
        wconvert_kernel<<<dim3(MLPD / 32, DIM / 32), blk, 0, stream>>>(
            W1 + (size_t)i * DIM * MLPD, W1t[i], DIM, MLPD);
        wconvert_kernel<<<dim3(DIM / 32, MLPD / 32), blk, 0, stream>>>(
            W2 + (size_t)i * MLPD * DIM, W2t[i], MLPD, DIM);
    }

    // ---- patch embedding: LN -> GEMM(+bias) -> LN ----
    ln_kernel<ushort_t><<<ROWS, blk, 0, stream>>>(patches, pe_ln1_g, xnbf);
    gemm_bf<64><<<dim3(DIM / 128, ROWS / 64), blk, 0, stream>>>(
        xnbf, peWt, pe_b, nullptr, peF, ROWS, DIM, DIM, 0, 0);
    ln_kernel<float><<<ROWS, blk, 0, stream>>>(peF, pe_ln2_g, out);

    float* x = out;  // residual stream lives in d_out
    for (int i = 0; i < LNUM; i++) {
        ln_kernel<ushort_t><<<ROWS, blk, 0, stream>>>(x, attn_ln_g + i * DIM, xnbf);
        gemm_bf<128><<<dim3(QKVD / 128, ROWS / 128), blk, 0, stream>>>(
            xnbf, Wqkvt[i], nullptr, nullptr, qkv, ROWS, QKVD, DIM, 1, 0);
        rmsrope_kernel<<<dim3(ROWS * NH / 4, 2), blk, 0, stream>>>(
            qkv, qn_g + i * NH * DH, kn_g + i * NH * DH, h_idx, w_idx);
        vtrans_kernel<<<dim3(BB * NH, DH / 32, NN / 32), blk, 0, stream>>>(qkv, vtg);
        attn_kernel<<<dim3(BB * NH, NN / 64), blk, 0, stream>>>(
            qkv, vtg, lengths, aob);
        gemm_bf<64><<<dim3(DIM / 128, ROWS / 64), blk, 0, stream>>>(
            aob, Wot[i], nullptr, x, x, ROWS, DIM, DIM, 0, 0);
        ln_kernel<ushort_t><<<ROWS, blk, 0, stream>>>(x, ff_ln_g + i * DIM, xnbf);
        gemm_bf<128><<<dim3(MLPD / 128, ROWS / 128), blk, 0, stream>>>(
            xnbf, W1t[i], b1 + i * MLPD, nullptr, hb, ROWS, MLPD, DIM, 1, 1);
        gemm_bf<64><<<dim3(DIM / 128, ROWS / 64), blk, 0, stream>>>(
            hb, W2t[i], b2 + i * DIM, x, x, ROWS, DIM, MLPD, 0, 0);
    }
    ln_kernel<float><<<ROWS, blk, 0, stream>>>(x, final_ln_g, out);
    mask_kernel<<<ROWS / 256, blk, 0, stream>>>(lengths, out + (size_t)ROWS * DIM);
}